// Round 8
// baseline (171.055 us; speedup 1.0000x reference)
//
#include <hip/hip_runtime.h>
#include <math.h>

#define NTOT 8704
#define BANKN 8192
#define NB 512
#define DIM 128
#define INVT (1.0f / 0.07f)
#define C2L 20.6099131801f  // (1/0.07) * log2(e)
#define NCHUNK 17
#define TPC 8               // col tiles per chunk (17*8*64 = 8704)
#define BN 64               // cols per tile

using short8 = __attribute__((ext_vector_type(8))) short;
using ushort8 = __attribute__((ext_vector_type(8))) unsigned short;
using f32x4 = __attribute__((ext_vector_type(4))) float;

static __device__ __forceinline__ ushort f2bf(float f) {
  union { float f; unsigned u; } v;
  v.f = f;
  unsigned r = v.u + 0x7fffu + ((v.u >> 16) & 1u);  // RNE
  return (ushort)(r >> 16);
}

static __device__ __forceinline__ float fast_exp2(float x) {
#if __has_builtin(__builtin_amdgcn_exp2f)
  return __builtin_amdgcn_exp2f(x);
#else
  return exp2f(x);
#endif
}

// ---------------- prep1: parallel histogram + zero zp (34 blocks) -----------
__global__ void prep1_kernel(const int* __restrict__ bank_labels,
                             const int* __restrict__ label,
                             int* __restrict__ cnt,
                             float* __restrict__ zp) {
  const int i = blockIdx.x * 256 + threadIdx.x;  // 34*256 == NTOT exactly
  reinterpret_cast<float4*>(zp)[i] = make_float4(0.f, 0.f, 0.f, 0.f);
  const int v = (i < BANKN) ? bank_labels[i] : label[i - BANKN];
  atomicAdd(&cnt[v], 1);
}

// ---------------- prep2: exclusive scan of 100 counts (1 block) -------------
__global__ void prep2_kernel(const int* __restrict__ cnt,
                             int* __restrict__ st, int* __restrict__ cur) {
  __shared__ int sc[128];
  const int tid = threadIdx.x;
  int mine = (tid < 100) ? cnt[tid] : 0;
  sc[tid] = mine;
  __syncthreads();
#pragma unroll
  for (int off = 1; off < 128; off <<= 1) {
    int add = (tid >= off) ? sc[tid - off] : 0;
    __syncthreads();
    sc[tid] += add;
    __syncthreads();
  }
  if (tid < 100) {
    const int ex = sc[tid] - mine;  // exclusive
    st[tid] = ex;
    cur[tid] = ex;
    if (tid == 99) st[100] = sc[99];
  }
}

// ---------------- prep3: parallel scatter (34 blocks) -----------------------
__global__ void prep3_kernel(const int* __restrict__ bank_labels,
                             const int* __restrict__ label,
                             const int* __restrict__ st, int* __restrict__ cur,
                             int* __restrict__ inv, int* __restrict__ lo,
                             int* __restrict__ hi) {
  const int i = blockIdx.x * 256 + threadIdx.x;
  const int v = (i < BANKN) ? bank_labels[i] : label[i - BANKN];
  const int p = atomicAdd(&cur[v], 1);
  inv[i] = p;
  lo[p] = st[v];
  hi[p] = st[v + 1];
}

// ---------------- pack: coalesced transpose + sorted row scatter ------------
__global__ void pack_kernel(const float* __restrict__ features,
                            const float* __restrict__ bank1,
                            const float* __restrict__ bank2,
                            const int* __restrict__ inv,
                            ushort* __restrict__ cf1b,
                            ushort* __restrict__ cf2b) {
  const int branch = blockIdx.z;
  ushort* __restrict__ dst = branch ? cf2b : cf1b;
  const int tx = threadIdx.x, ty = threadIdx.y;
  const int bx = blockIdx.x, by = blockIdx.y;
  if (bx < 256) {
    const float* __restrict__ src = branch ? bank1 : bank2;
    __shared__ float tile[32][33];
    const int col = bx * 32 + tx;  // original cf row (bank column)
#pragma unroll
    for (int s = 0; s < 32; s += 8)
      tile[ty + s][tx] = src[(size_t)(by * 32 + ty + s) * BANKN + col];
    __syncthreads();
    const int k = by * 32 + tx;
#pragma unroll
    for (int s = 0; s < 32; s += 8) {
      const int p = inv[bx * 32 + ty + s];
      dst[(size_t)p * DIM + k] = f2bf(tile[tx][ty + s]);
    }
  } else {
#pragma unroll
    for (int s = 0; s < 32; s += 8) {
      const int jr = (bx - 256) * 32 + ty + s;
      const int k = by * 32 + tx;
      const float v = features[(size_t)(branch * NB + jr) * DIM + k];
      const int p = inv[BANKN + jr];
      dst[(size_t)p * DIM + k] = f2bf(v);
    }
  }
}

// ---------------- main: MFMA + interval-sorted masked reductions ------------
// (r7 verbatim: 3 LDS buffers, depth-2 prefetch, raw s_barrier + vmcnt(4))
__global__ __launch_bounds__(256) void supcon_mfma_kernel(
    const ushort* __restrict__ cf1b, const ushort* __restrict__ cf2b,
    const int* __restrict__ lo, const int* __restrict__ hi,
    float* __restrict__ zp) {
  const int rb = blockIdx.x;      // 0..67 row block (128 rows)
  const int chunk = blockIdx.y;   // 0..16
  const int branch = blockIdx.z;  // 0..1
  const ushort* __restrict__ cf = branch ? cf2b : cf1b;

  const int tid = threadIdx.x;
  const int wid = tid >> 6, lane = tid & 63;
  const int l15 = lane & 15, l4 = lane >> 4;
  const int rowW = rb * 128 + wid * 32;  // wave owns rows [rowW, rowW+32)

  __shared__ ushort Bt[3][BN * DIM];  // 3 x 16KB

  short8 a[2][4];
#pragma unroll
  for (int rt = 0; rt < 2; ++rt) {
    const int r = rowW + rt * 16 + l15;
#pragma unroll
    for (int ks = 0; ks < 4; ++ks)
      a[rt][ks] = *reinterpret_cast<const short8*>(cf + (size_t)r * DIM + ks * 32 + l4 * 8);
  }
  int rlo[2][4], rhi[2][4];
#pragma unroll
  for (int rt = 0; rt < 2; ++rt)
#pragma unroll
    for (int rg = 0; rg < 4; ++rg) {
      const int rr = rowW + rt * 16 + l4 * 4 + rg;
      rlo[rt][rg] = lo[rr];
      rhi[rt][rg] = hi[rr];
    }
  const int u_lo = lo[rowW];
  const int u_hi = hi[rowW + 31];
  const int lo_last = lo[rowW + 31];
  const int hi_first = hi[rowW];

  float Zr[2][4] = {};
  float Pr[2][4] = {};

  auto STAGE = [&](int t, int buf) {
    const int col0 = (chunk * TPC + t) * BN;
#pragma unroll
    for (int it = 0; it < 4; ++it) {
      const int o = it * 256 + tid;  // 16B-chunk index 0..1023
      const int row = o >> 4, cc = o & 15;
      const ushort* src =
          cf + (size_t)(col0 + row) * DIM + ((cc ^ (row & 15)) * 8);
      ushort* dst = &Bt[buf][(it * 256 + wid * 64) * 8];  // wave-uniform base
      __builtin_amdgcn_global_load_lds(
          (const __attribute__((address_space(1))) void*)src,
          (__attribute__((address_space(3))) void*)dst, 16, 0, 0);
    }
  };

  STAGE(0, 0);
  STAGE(1, 1);

  for (int t = 0; t < TPC; ++t) {
    if (t + 1 < TPC)
      asm volatile("s_waitcnt vmcnt(4)" ::: "memory");
    else
      asm volatile("s_waitcnt vmcnt(0)" ::: "memory");
    __builtin_amdgcn_s_barrier();
    if (t + 2 < TPC) STAGE(t + 2, (t + 2) % 3);

    const int col0 = (chunk * TPC + t) * BN;
    const ushort* __restrict__ B = &Bt[t % 3][0];

    f32x4 acc[2][4];
#pragma unroll
    for (int rt = 0; rt < 2; ++rt)
#pragma unroll
      for (int ct = 0; ct < 4; ++ct) acc[rt][ct] = (f32x4){0.f, 0.f, 0.f, 0.f};

#pragma unroll
    for (int ks = 0; ks < 4; ++ks) {
      short8 b[4];
#pragma unroll
      for (int ct = 0; ct < 4; ++ct) {
        const int r = ct * 16 + l15;
        const int swz = (ks * 4 + l4) ^ (r & 15);
        b[ct] = *reinterpret_cast<const short8*>(&B[r * DIM + swz * 8]);
      }
#pragma unroll
      for (int rt = 0; rt < 2; ++rt)
#pragma unroll
        for (int ct = 0; ct < 4; ++ct)
          acc[rt][ct] = __builtin_amdgcn_mfma_f32_16x16x32_bf16(
              a[rt][ks], b[ct], acc[rt][ct], 0, 0, 0);
    }

    if (col0 + BN <= u_lo || col0 >= u_hi) {
#pragma unroll
      for (int ct = 0; ct < 4; ++ct)
#pragma unroll
        for (int rt = 0; rt < 2; ++rt)
#pragma unroll
          for (int rg = 0; rg < 4; ++rg)
            Zr[rt][rg] += fast_exp2(fmaf(acc[rt][ct][rg], C2L, -C2L));
    } else if (col0 >= lo_last && col0 + BN <= hi_first) {
#pragma unroll
      for (int ct = 0; ct < 4; ++ct)
#pragma unroll
        for (int rt = 0; rt < 2; ++rt)
#pragma unroll
          for (int rg = 0; rg < 4; ++rg) Pr[rt][rg] += acc[rt][ct][rg];
    } else {
#pragma unroll
      for (int ct = 0; ct < 4; ++ct) {
        const int c = col0 + ct * 16 + l15;
#pragma unroll
        for (int rt = 0; rt < 2; ++rt)
#pragma unroll
          for (int rg = 0; rg < 4; ++rg) {
            const float v = acc[rt][ct][rg];
            const float e = fast_exp2(fmaf(v, C2L, -C2L));
            const bool s = (c >= rlo[rt][rg]) && (c < rhi[rt][rg]);
            Zr[rt][rg] += s ? 0.0f : e;
            Pr[rt][rg] += s ? v : 0.0f;
          }
      }
    }
  }

  float* Zrow = zp;             // [2][NTOT]
  float* Prow = zp + 2 * NTOT;  // [2][NTOT]
#pragma unroll
  for (int rt = 0; rt < 2; ++rt)
#pragma unroll
    for (int rg = 0; rg < 4; ++rg) {
      float z = Zr[rt][rg], p = Pr[rt][rg];
#pragma unroll
      for (int off = 1; off < 16; off <<= 1) {
        z += __shfl_xor(z, off);
        p += __shfl_xor(p, off);
      }
      if (l15 == 0) {
        const int row = rowW + rt * 16 + l4 * 4 + rg;
        atomicAdd(&Zrow[branch * NTOT + row], z);
        atomicAdd(&Prow[branch * NTOT + row], p);
      }
    }
}

// ---------------- loss: per-row loss -> scalar (single block) ---------------
__global__ __launch_bounds__(1024) void loss_kernel(const float* __restrict__ zp,
                                                    const int* __restrict__ lo,
                                                    const int* __restrict__ hi,
                                                    float* __restrict__ out) {
  const int tid = threadIdx.x;
  const float* Zrow = zp;
  const float* Prow = zp + 2 * NTOT;
  float local = 0.f;
  for (int idx = tid; idx < 2 * NTOT; idx += 1024) {
    const int row = (idx >= NTOT) ? idx - NTOT : idx;
    const float z = Zrow[idx];
    const float p = Prow[idx];
    const float C = (float)(hi[row] - lo[row] - 1);
    const float denom = INVT + logf(z);
    local += -((INVT * (p - 1.0f)) / C - denom);
  }
  __shared__ float s[1024];
  s[tid] = local;
  __syncthreads();
  for (int st = 512; st > 0; st >>= 1) {
    if (tid < st) s[tid] += s[tid + st];
    __syncthreads();
  }
  if (tid == 0) {
    const float v = s[0] / (2.0f * NTOT);
    out[0] = v; out[1] = v; out[2] = v;
  }
}

// ---------------------------------------------------------------------------
extern "C" void kernel_launch(void* const* d_in, const int* in_sizes, int n_in,
                              void* d_out, int out_size, void* d_ws,
                              size_t ws_size, hipStream_t stream) {
  const float* features = (const float*)d_in[0];  // (1024,1,128) f32
  const int* label = (const int*)d_in[1];         // (512,) i32
  const float* bank1 = (const float*)d_in[2];     // (128,8192) f32
  const float* bank2 = (const float*)d_in[3];     // (128,8192) f32
  const int* bank_labels = (const int*)d_in[4];   // (8192,) i32
  float* out = (float*)d_out;

  char* ws = (char*)d_ws;
  ushort* cf1b = (ushort*)(ws);            // 2,228,224 B
  ushort* cf2b = (ushort*)(ws + 2228224);  // 2,228,224 B
  int* inv = (int*)(ws + 4456448);         // 34,816 B
  int* lo = (int*)(ws + 4491264);          // 34,816 B
  int* hi = (int*)(ws + 4526080);          // 34,816 B
  float* zp = (float*)(ws + 4560896);      // 139,264 B (Z[2][N], P[2][N])
  int* cnt = (int*)(ws + 4700160);         // 400 B
  int* st = (int*)(ws + 4700560);          // 404 B
  int* cur = (int*)(ws + 4700964);         // 400 B

  // zero cnt/st/cur (graph-capturable memset node)
  hipMemsetAsync(ws + 4700160, 0, 1204, stream);

  prep1_kernel<<<dim3(34), dim3(256), 0, stream>>>(bank_labels, label, cnt,
                                                   zp);
  prep2_kernel<<<dim3(1), dim3(128), 0, stream>>>(cnt, st, cur);
  prep3_kernel<<<dim3(34), dim3(256), 0, stream>>>(bank_labels, label, st, cur,
                                                   inv, lo, hi);
  pack_kernel<<<dim3(272, DIM / 32, 2), dim3(32, 8), 0, stream>>>(
      features, bank1, bank2, inv, cf1b, cf2b);
  supcon_mfma_kernel<<<dim3(NTOT / 128, NCHUNK, 2), dim3(256), 0, stream>>>(
      cf1b, cf2b, lo, hi, zp);
  loss_kernel<<<dim3(1), dim3(1024), 0, stream>>>(zp, lo, hi, out);
}

// Round 9
// 158.985 us; speedup vs baseline: 1.0759x; 1.0759x over previous
//
#include <hip/hip_runtime.h>
#include <math.h>

#define NTOT 8704
#define BANKN 8192
#define NB 512
#define DIM 128
#define INVT (1.0f / 0.07f)
#define C2L 20.6099131801f  // (1/0.07) * log2(e)
#define NCHUNK 17
#define TPC 8               // col tiles per chunk (17*8*64 = 8704)
#define BN 64               // cols per tile

using short8 = __attribute__((ext_vector_type(8))) short;
using ushort8 = __attribute__((ext_vector_type(8))) unsigned short;
using f32x4 = __attribute__((ext_vector_type(4))) float;

static __device__ __forceinline__ ushort f2bf(float f) {
  union { float f; unsigned u; } v;
  v.f = f;
  unsigned r = v.u + 0x7fffu + ((v.u >> 16) & 1u);  // RNE
  return (ushort)(r >> 16);
}

static __device__ __forceinline__ float fast_exp2(float x) {
#if __has_builtin(__builtin_amdgcn_exp2f)
  return __builtin_amdgcn_exp2f(x);
#else
  return exp2f(x);
#endif
}

// ---------------- pack: transpose banks + copy features (identity order) ----
// Also materializes lab_all and zeroes zp (no separate prep chain).
__global__ void pack_kernel(const float* __restrict__ features,
                            const float* __restrict__ bank1,
                            const float* __restrict__ bank2,
                            const int* __restrict__ bank_labels,
                            const int* __restrict__ label,
                            ushort* __restrict__ cf1b,
                            ushort* __restrict__ cf2b,
                            int* __restrict__ lab_all,
                            float* __restrict__ zp) {
  const int branch = blockIdx.z;
  ushort* __restrict__ dst = branch ? cf2b : cf1b;
  const int tx = threadIdx.x, ty = threadIdx.y;
  const int bx = blockIdx.x, by = blockIdx.y;
  const int tid = ty * 32 + tx;

  // side duty (34 blocks' worth): zero zp (8704 float4) and write lab_all
  if (branch == 0 && by == 0 && bx < 34) {
    const int i = bx * 256 + tid;  // 34*256 == 8704 == NTOT
    reinterpret_cast<float4*>(zp)[i] = make_float4(0.f, 0.f, 0.f, 0.f);
    lab_all[i] = (i < BANKN) ? bank_labels[i] : label[i - BANKN];
  }

  if (bx < 256) {
    const float* __restrict__ src = branch ? bank1 : bank2;
    __shared__ float tile[32][33];
    const int col = bx * 32 + tx;  // cf row (bank column)
#pragma unroll
    for (int s = 0; s < 32; s += 8)
      tile[ty + s][tx] = src[(size_t)(by * 32 + ty + s) * BANKN + col];
    __syncthreads();
    const int k = by * 32 + tx;
#pragma unroll
    for (int s = 0; s < 32; s += 8)
      dst[(size_t)(bx * 32 + ty + s) * DIM + k] = f2bf(tile[tx][ty + s]);
  } else {
#pragma unroll
    for (int s = 0; s < 32; s += 8) {
      const int jr = (bx - 256) * 32 + ty + s;
      const int k = by * 32 + tx;
      const float v = features[(size_t)(branch * NB + jr) * DIM + k];
      dst[(size_t)(BANKN + jr) * DIM + k] = f2bf(v);
    }
  }
}

// ---------------- main: MFMA + per-element label-masked reductions ----------
// r7 engine: 3 LDS buffers, depth-2 prefetch, raw s_barrier + counted vmcnt(4).
__global__ __launch_bounds__(256) void supcon_mfma_kernel(
    const ushort* __restrict__ cf1b, const ushort* __restrict__ cf2b,
    const int* __restrict__ lab_all, float* __restrict__ zp) {
  const int rb = blockIdx.x;      // 0..67 row block (128 rows)
  const int chunk = blockIdx.y;   // 0..16
  const int branch = blockIdx.z;  // 0..1
  const ushort* __restrict__ cf = branch ? cf2b : cf1b;

  const int tid = threadIdx.x;
  const int wid = tid >> 6, lane = tid & 63;
  const int l15 = lane & 15, l4 = lane >> 4;
  const int rowW = rb * 128 + wid * 32;  // wave owns rows [rowW, rowW+32)

  __shared__ ushort Bt[3][BN * DIM];  // 3 x 16KB

  // ---- A fragments: 32 rows x K=128 per wave ----
  short8 a[2][4];
#pragma unroll
  for (int rt = 0; rt < 2; ++rt) {
    const int r = rowW + rt * 16 + l15;
#pragma unroll
    for (int ks = 0; ks < 4; ++ks)
      a[rt][ks] = *reinterpret_cast<const short8*>(cf + (size_t)r * DIM + ks * 32 + l4 * 8);
  }
  // per-accumulated-row labels
  int rlab[2][4];
#pragma unroll
  for (int rt = 0; rt < 2; ++rt)
#pragma unroll
    for (int rg = 0; rg < 4; ++rg)
      rlab[rt][rg] = lab_all[rowW + rt * 16 + l4 * 4 + rg];

  float Zr[2][4] = {};
  float Pr[2][4] = {};

  auto STAGE = [&](int t, int buf) {
    const int col0 = (chunk * TPC + t) * BN;
#pragma unroll
    for (int it = 0; it < 4; ++it) {
      const int o = it * 256 + tid;  // 16B-chunk index 0..1023
      const int row = o >> 4, cc = o & 15;
      const ushort* src =
          cf + (size_t)(col0 + row) * DIM + ((cc ^ (row & 15)) * 8);
      ushort* dst = &Bt[buf][(it * 256 + wid * 64) * 8];  // wave-uniform base
      __builtin_amdgcn_global_load_lds(
          (const __attribute__((address_space(1))) void*)src,
          (__attribute__((address_space(3))) void*)dst, 16, 0, 0);
    }
  };

  STAGE(0, 0);
  STAGE(1, 1);

  for (int t = 0; t < TPC; ++t) {
    if (t + 1 < TPC)
      asm volatile("s_waitcnt vmcnt(4)" ::: "memory");
    else
      asm volatile("s_waitcnt vmcnt(0)" ::: "memory");
    __builtin_amdgcn_s_barrier();
    if (t + 2 < TPC) STAGE(t + 2, (t + 2) % 3);

    const int col0 = (chunk * TPC + t) * BN;

    // column labels for this tile (hoisted: overlaps with ds_read latency)
    int clab[4];
#pragma unroll
    for (int ct = 0; ct < 4; ++ct) clab[ct] = lab_all[col0 + ct * 16 + l15];

    const ushort* __restrict__ B = &Bt[t % 3][0];

    f32x4 acc[2][4];
#pragma unroll
    for (int rt = 0; rt < 2; ++rt)
#pragma unroll
      for (int ct = 0; ct < 4; ++ct) acc[rt][ct] = (f32x4){0.f, 0.f, 0.f, 0.f};

#pragma unroll
    for (int ks = 0; ks < 4; ++ks) {
      short8 b[4];
#pragma unroll
      for (int ct = 0; ct < 4; ++ct) {
        const int r = ct * 16 + l15;
        const int swz = (ks * 4 + l4) ^ (r & 15);
        b[ct] = *reinterpret_cast<const short8*>(&B[r * DIM + swz * 8]);
      }
#pragma unroll
      for (int rt = 0; rt < 2; ++rt)
#pragma unroll
        for (int ct = 0; ct < 4; ++ct)
          acc[rt][ct] = __builtin_amdgcn_mfma_f32_16x16x32_bf16(
              a[rt][ks], b[ct], acc[rt][ct], 0, 0, 0);
    }

    // ---- epilogue: per-element label mask; diag excluded exactly ----
#pragma unroll
    for (int ct = 0; ct < 4; ++ct) {
      const int c = col0 + ct * 16 + l15;
      const int cl = clab[ct];
#pragma unroll
      for (int rt = 0; rt < 2; ++rt)
#pragma unroll
        for (int rg = 0; rg < 4; ++rg) {
          const int r = rowW + rt * 16 + l4 * 4 + rg;
          const float v = acc[rt][ct][rg];
          const float e = fast_exp2(fmaf(v, C2L, -C2L));
          const bool same = (rlab[rt][rg] == cl);
          Zr[rt][rg] += same ? 0.0f : e;
          const bool pos = same && (c != r);
          Pr[rt][rg] += pos ? v : 0.0f;
        }
    }
  }

  // ---- cross-lane reduce over l15 group, then atomic accumulate ----
  float* Zrow = zp;             // [2][NTOT]
  float* Prow = zp + 2 * NTOT;  // [2][NTOT]
#pragma unroll
  for (int rt = 0; rt < 2; ++rt)
#pragma unroll
    for (int rg = 0; rg < 4; ++rg) {
      float z = Zr[rt][rg], p = Pr[rt][rg];
#pragma unroll
      for (int off = 1; off < 16; off <<= 1) {
        z += __shfl_xor(z, off);
        p += __shfl_xor(p, off);
      }
      if (l15 == 0) {
        const int row = rowW + rt * 16 + l4 * 4 + rg;
        atomicAdd(&Zrow[branch * NTOT + row], z);
        atomicAdd(&Prow[branch * NTOT + row], p);
      }
    }
}

// ---------------- loss: histogram + per-row loss -> scalar (1 block) --------
__global__ __launch_bounds__(1024) void loss_kernel(
    const float* __restrict__ zp, const int* __restrict__ bank_labels,
    const int* __restrict__ label, float* __restrict__ out) {
  const int tid = threadIdx.x;
  __shared__ int h[100];
  __shared__ float s[1024];
  if (tid < 100) h[tid] = 0;
  __syncthreads();
  for (int i = tid; i < NTOT; i += 1024) {
    const int v = (i < BANKN) ? bank_labels[i] : label[i - BANKN];
    atomicAdd(&h[v], 1);
  }
  __syncthreads();
  const float* Zrow = zp;
  const float* Prow = zp + 2 * NTOT;
  float local = 0.f;
  for (int idx = tid; idx < 2 * NTOT; idx += 1024) {
    const int row = (idx >= NTOT) ? idx - NTOT : idx;
    const int rl = (row < BANKN) ? bank_labels[row] : label[row - BANKN];
    const float z = Zrow[idx];
    const float p = Prow[idx];  // diag already excluded in main
    const float C = (float)(h[rl] - 1);
    const float denom = INVT + logf(z);
    local += -((INVT * p) / C - denom);
  }
  s[tid] = local;
  __syncthreads();
  for (int st = 512; st > 0; st >>= 1) {
    if (tid < st) s[tid] += s[tid + st];
    __syncthreads();
  }
  if (tid == 0) {
    const float v = s[0] / (2.0f * NTOT);
    out[0] = v; out[1] = v; out[2] = v;
  }
}

// ---------------------------------------------------------------------------
extern "C" void kernel_launch(void* const* d_in, const int* in_sizes, int n_in,
                              void* d_out, int out_size, void* d_ws,
                              size_t ws_size, hipStream_t stream) {
  const float* features = (const float*)d_in[0];  // (1024,1,128) f32
  const int* label = (const int*)d_in[1];         // (512,) i32
  const float* bank1 = (const float*)d_in[2];     // (128,8192) f32
  const float* bank2 = (const float*)d_in[3];     // (128,8192) f32
  const int* bank_labels = (const int*)d_in[4];   // (8192,) i32
  float* out = (float*)d_out;

  char* ws = (char*)d_ws;
  ushort* cf1b = (ushort*)(ws);            // 2,228,224 B
  ushort* cf2b = (ushort*)(ws + 2228224);  // 2,228,224 B
  int* lab_all = (int*)(ws + 4456448);     // 34,816 B
  float* zp = (float*)(ws + 4491264);      // 139,264 B (Z[2][N], P[2][N])

  pack_kernel<<<dim3(272, DIM / 32, 2), dim3(32, 8), 0, stream>>>(
      features, bank1, bank2, bank_labels, label, cf1b, cf2b, lab_all, zp);
  supcon_mfma_kernel<<<dim3(NTOT / 128, NCHUNK, 2), dim3(256), 0, stream>>>(
      cf1b, cf2b, lab_all, zp);
  loss_kernel<<<dim3(1), dim3(1024), 0, stream>>>(zp, bank_labels, label, out);
}

// Round 10
// 151.041 us; speedup vs baseline: 1.1325x; 1.0526x over previous
//
#include <hip/hip_runtime.h>
#include <math.h>

#define NTOT 8704
#define BANKN 8192
#define NB 512
#define DIM 128
#define INVT (1.0f / 0.07f)
#define C2L 20.6099131801f  // (1/0.07) * log2(e)
#define NCHUNK 17
#define TPC 8               // col tiles per chunk (17*8*64 = 8704)
#define BN 64               // cols per tile

using short8 = __attribute__((ext_vector_type(8))) short;
using ushort8 = __attribute__((ext_vector_type(8))) unsigned short;
using f32x4 = __attribute__((ext_vector_type(4))) float;

static __device__ __forceinline__ ushort f2bf(float f) {
  union { float f; unsigned u; } v;
  v.f = f;
  unsigned r = v.u + 0x7fffu + ((v.u >> 16) & 1u);  // RNE
  return (ushort)(r >> 16);
}

static __device__ __forceinline__ float fast_exp2(float x) {
#if __has_builtin(__builtin_amdgcn_exp2f)
  return __builtin_amdgcn_exp2f(x);
#else
  return exp2f(x);
#endif
}

// ---------------- prep: counting sort via 16 per-wave sub-histograms --------
// inv[i] = sorted position of original row i; lo/hi[p] = class interval.
__global__ __launch_bounds__(1024) void prep_kernel(
    const int* __restrict__ bank_labels, const int* __restrict__ label,
    int* __restrict__ inv, int* __restrict__ lo, int* __restrict__ hi) {
  __shared__ int h[16][100];
  __shared__ int st[101];
  __shared__ int sc[128];
  const int tid = threadIdx.x;
  const int w = tid >> 6;
  for (int i = tid; i < 1600; i += 1024) (&h[0][0])[i] = 0;
  __syncthreads();
  // pass 1: per-wave histograms
  for (int i = tid; i < NTOT; i += 1024) {
    const int v = (i < BANKN) ? bank_labels[i] : label[i - BANKN];
    atomicAdd(&h[w][v], 1);
  }
  __syncthreads();
  // total per class, parallel exclusive scan
  int tot = 0;
  if (tid < 128) {
    if (tid < 100) {
#pragma unroll
      for (int w2 = 0; w2 < 16; ++w2) tot += h[w2][tid];
    }
    sc[tid] = tot;
  }
  __syncthreads();
#pragma unroll
  for (int off = 1; off < 128; off <<= 1) {
    int add = 0;
    if (tid < 128 && tid >= off) add = sc[tid - off];
    __syncthreads();
    if (tid < 128) sc[tid] += add;
    __syncthreads();
  }
  if (tid < 100) {
    st[tid] = sc[tid] - tot;  // exclusive
    if (tid == 99) st[100] = sc[99];
  }
  __syncthreads();
  // per-wave base offsets
  if (tid < 100) {
    int base = st[tid];
#pragma unroll
    for (int w2 = 0; w2 < 16; ++w2) {
      const int t = h[w2][tid];
      h[w2][tid] = base;
      base += t;
    }
  }
  __syncthreads();
  // pass 2: unique positions per element
  for (int i = tid; i < NTOT; i += 1024) {
    const int v = (i < BANKN) ? bank_labels[i] : label[i - BANKN];
    const int p = atomicAdd(&h[w][v], 1);
    inv[i] = p;
    lo[p] = st[v];
    hi[p] = st[v + 1];
  }
}

// ---------------- pack: coalesced transpose + sorted row scatter; zero zp ---
__global__ void pack_kernel(const float* __restrict__ features,
                            const float* __restrict__ bank1,
                            const float* __restrict__ bank2,
                            const int* __restrict__ inv,
                            ushort* __restrict__ cf1b,
                            ushort* __restrict__ cf2b,
                            float* __restrict__ zp) {
  const int branch = blockIdx.z;
  ushort* __restrict__ dst = branch ? cf2b : cf1b;
  const int tx = threadIdx.x, ty = threadIdx.y;
  const int bx = blockIdx.x, by = blockIdx.y;
  const int tid = ty * 32 + tx;
  // zero Z/P accumulators
  if (branch == 0 && by == 0 && bx < 34) {
    const int i = bx * 256 + tid;  // 34*256 == NTOT
    reinterpret_cast<float4*>(zp)[i] = make_float4(0.f, 0.f, 0.f, 0.f);
  }
  if (bx < 256) {
    const float* __restrict__ src = branch ? bank1 : bank2;
    __shared__ float tile[32][33];
    const int col = bx * 32 + tx;  // original cf row (bank column)
#pragma unroll
    for (int s = 0; s < 32; s += 8)
      tile[ty + s][tx] = src[(size_t)(by * 32 + ty + s) * BANKN + col];
    __syncthreads();
    const int k = by * 32 + tx;
#pragma unroll
    for (int s = 0; s < 32; s += 8) {
      const int p = inv[bx * 32 + ty + s];
      dst[(size_t)p * DIM + k] = f2bf(tile[tx][ty + s]);
    }
  } else {
#pragma unroll
    for (int s = 0; s < 32; s += 8) {
      const int jr = (bx - 256) * 32 + ty + s;
      const int k = by * 32 + tx;
      const float v = features[(size_t)(branch * NB + jr) * DIM + k];
      const int p = inv[BANKN + jr];
      dst[(size_t)p * DIM + k] = f2bf(v);
    }
  }
}

// ---------------- main: MFMA + interval-sorted masked reductions ------------
// 2-buffer double-buffer (32 KB LDS -> 5 blocks/CU), stage-after-barrier.
__global__ __launch_bounds__(256) void supcon_mfma_kernel(
    const ushort* __restrict__ cf1b, const ushort* __restrict__ cf2b,
    const int* __restrict__ lo, const int* __restrict__ hi,
    float* __restrict__ zp) {
  const int rb = blockIdx.x;      // 0..67 row block (128 rows)
  const int chunk = blockIdx.y;   // 0..16
  const int branch = blockIdx.z;  // 0..1
  const ushort* __restrict__ cf = branch ? cf2b : cf1b;

  const int tid = threadIdx.x;
  const int wid = tid >> 6, lane = tid & 63;
  const int l15 = lane & 15, l4 = lane >> 4;
  const int rowW = rb * 128 + wid * 32;  // wave owns rows [rowW, rowW+32)

  __shared__ ushort Bt[2][BN * DIM];  // 2 x 16KB = 32 KB total

  // ---- A fragments: 32 rows x K=128 per wave ----
  short8 a[2][4];
#pragma unroll
  for (int rt = 0; rt < 2; ++rt) {
    const int r = rowW + rt * 16 + l15;
#pragma unroll
    for (int ks = 0; ks < 4; ++ks)
      a[rt][ks] = *reinterpret_cast<const short8*>(cf + (size_t)r * DIM + ks * 32 + l4 * 8);
  }
  // per-accumulated-row positive intervals (registers)
  int rlo[2][4], rhi[2][4];
#pragma unroll
  for (int rt = 0; rt < 2; ++rt)
#pragma unroll
    for (int rg = 0; rg < 4; ++rg) {
      const int rr = rowW + rt * 16 + l4 * 4 + rg;
      rlo[rt][rg] = lo[rr];
      rhi[rt][rg] = hi[rr];
    }
  // wave-uniform interval hull (rows sorted)
  const int u_lo = lo[rowW];
  const int u_hi = hi[rowW + 31];
  const int lo_last = lo[rowW + 31];
  const int hi_first = hi[rowW];

  float Zr[2][4] = {};
  float Pr[2][4] = {};

  // ---- stage: global -> LDS, linear dest, inverse-swizzled source ----
  auto STAGE = [&](int t, int buf) {
    const int col0 = (chunk * TPC + t) * BN;
#pragma unroll
    for (int it = 0; it < 4; ++it) {
      const int o = it * 256 + tid;  // 16B-chunk index 0..1023
      const int row = o >> 4, cc = o & 15;
      const ushort* src =
          cf + (size_t)(col0 + row) * DIM + ((cc ^ (row & 15)) * 8);
      ushort* dst = &Bt[buf][(it * 256 + wid * 64) * 8];  // wave-uniform base
      __builtin_amdgcn_global_load_lds(
          (const __attribute__((address_space(1))) void*)src,
          (__attribute__((address_space(3))) void*)dst, 16, 0, 0);
    }
  };

  STAGE(0, 0);

  for (int t = 0; t < TPC; ++t) {
    // own stage loads for tile t retired (issued last iter; latency covered
    // by the previous compute phase)
    asm volatile("s_waitcnt vmcnt(0)" ::: "memory");
    // all waves' stage-writes for tile t visible; iter t-1 reads of the
    // other buffer finished -> safe to overwrite it below
    __builtin_amdgcn_s_barrier();
    if (t + 1 < TPC) STAGE(t + 1, (t + 1) & 1);

    const int col0 = (chunk * TPC + t) * BN;
    const ushort* __restrict__ B = &Bt[t & 1][0];

    f32x4 acc[2][4];
#pragma unroll
    for (int rt = 0; rt < 2; ++rt)
#pragma unroll
      for (int ct = 0; ct < 4; ++ct) acc[rt][ct] = (f32x4){0.f, 0.f, 0.f, 0.f};

#pragma unroll
    for (int ks = 0; ks < 4; ++ks) {
      short8 b[4];
#pragma unroll
      for (int ct = 0; ct < 4; ++ct) {
        const int r = ct * 16 + l15;
        const int swz = (ks * 4 + l4) ^ (r & 15);
        b[ct] = *reinterpret_cast<const short8*>(&B[r * DIM + swz * 8]);
      }
#pragma unroll
      for (int rt = 0; rt < 2; ++rt)
#pragma unroll
        for (int ct = 0; ct < 4; ++ct)
          acc[rt][ct] = __builtin_amdgcn_mfma_f32_16x16x32_bf16(
              a[rt][ks], b[ct], acc[rt][ct], 0, 0, 0);
    }

    // ---- epilogue: tile-uniform classification per wave (sorted rows) ----
    if (col0 + BN <= u_lo || col0 >= u_hi) {
      // pure negative: Z += exp2((v-1)/T * log2e)
#pragma unroll
      for (int ct = 0; ct < 4; ++ct)
#pragma unroll
        for (int rt = 0; rt < 2; ++rt)
#pragma unroll
          for (int rg = 0; rg < 4; ++rg)
            Zr[rt][rg] += fast_exp2(fmaf(acc[rt][ct][rg], C2L, -C2L));
    } else if (col0 >= lo_last && col0 + BN <= hi_first) {
      // pure positive for every wave row: P += v (diag included; -1 later)
#pragma unroll
      for (int ct = 0; ct < 4; ++ct)
#pragma unroll
        for (int rt = 0; rt < 2; ++rt)
#pragma unroll
          for (int rg = 0; rg < 4; ++rg) Pr[rt][rg] += acc[rt][ct][rg];
    } else {
      // mixed: per-element interval test (register lo/hi)
#pragma unroll
      for (int ct = 0; ct < 4; ++ct) {
        const int c = col0 + ct * 16 + l15;
#pragma unroll
        for (int rt = 0; rt < 2; ++rt)
#pragma unroll
          for (int rg = 0; rg < 4; ++rg) {
            const float v = acc[rt][ct][rg];
            const float e = fast_exp2(fmaf(v, C2L, -C2L));
            const bool s = (c >= rlo[rt][rg]) && (c < rhi[rt][rg]);
            Zr[rt][rg] += s ? 0.0f : e;
            Pr[rt][rg] += s ? v : 0.0f;
          }
      }
    }
  }

  // ---- cross-lane reduce over l15 group, then atomic accumulate ----
  float* Zrow = zp;             // [2][NTOT]
  float* Prow = zp + 2 * NTOT;  // [2][NTOT]
#pragma unroll
  for (int rt = 0; rt < 2; ++rt)
#pragma unroll
    for (int rg = 0; rg < 4; ++rg) {
      float z = Zr[rt][rg], p = Pr[rt][rg];
#pragma unroll
      for (int off = 1; off < 16; off <<= 1) {
        z += __shfl_xor(z, off);
        p += __shfl_xor(p, off);
      }
      if (l15 == 0) {
        const int row = rowW + rt * 16 + l4 * 4 + rg;
        atomicAdd(&Zrow[branch * NTOT + row], z);
        atomicAdd(&Prow[branch * NTOT + row], p);
      }
    }
}

// ---------------- loss: per-row loss -> scalar (single block) ---------------
__global__ __launch_bounds__(1024) void loss_kernel(const float* __restrict__ zp,
                                                    const int* __restrict__ lo,
                                                    const int* __restrict__ hi,
                                                    float* __restrict__ out) {
  const int tid = threadIdx.x;
  const float* Zrow = zp;
  const float* Prow = zp + 2 * NTOT;
  float local = 0.f;
  for (int idx = tid; idx < 2 * NTOT; idx += 1024) {
    const int row = (idx >= NTOT) ? idx - NTOT : idx;
    const float z = Zrow[idx];
    const float p = Prow[idx];
    const float C = (float)(hi[row] - lo[row] - 1);
    const float denom = INVT + logf(z);
    local += -((INVT * (p - 1.0f)) / C - denom);
  }
  __shared__ float s[1024];
  s[tid] = local;
  __syncthreads();
  for (int st = 512; st > 0; st >>= 1) {
    if (tid < st) s[tid] += s[tid + st];
    __syncthreads();
  }
  if (tid == 0) {
    const float v = s[0] / (2.0f * NTOT);
    out[0] = v; out[1] = v; out[2] = v;
  }
}

// ---------------------------------------------------------------------------
extern "C" void kernel_launch(void* const* d_in, const int* in_sizes, int n_in,
                              void* d_out, int out_size, void* d_ws,
                              size_t ws_size, hipStream_t stream) {
  const float* features = (const float*)d_in[0];  // (1024,1,128) f32
  const int* label = (const int*)d_in[1];         // (512,) i32
  const float* bank1 = (const float*)d_in[2];     // (128,8192) f32
  const float* bank2 = (const float*)d_in[3];     // (128,8192) f32
  const int* bank_labels = (const int*)d_in[4];   // (8192,) i32
  float* out = (float*)d_out;

  char* ws = (char*)d_ws;
  ushort* cf1b = (ushort*)(ws);            // 2,228,224 B
  ushort* cf2b = (ushort*)(ws + 2228224);  // 2,228,224 B
  int* inv = (int*)(ws + 4456448);         // 34,816 B
  int* lo = (int*)(ws + 4491264);          // 34,816 B
  int* hi = (int*)(ws + 4526080);          // 34,816 B
  float* zp = (float*)(ws + 4560896);      // 139,264 B (Z[2][N], P[2][N])

  prep_kernel<<<dim3(1), dim3(1024), 0, stream>>>(bank_labels, label, inv, lo,
                                                  hi);
  pack_kernel<<<dim3(272, DIM / 32, 2), dim3(32, 8), 0, stream>>>(
      features, bank1, bank2, inv, cf1b, cf2b, zp);
  supcon_mfma_kernel<<<dim3(NTOT / 128, NCHUNK, 2), dim3(256), 0, stream>>>(
      cf1b, cf2b, lo, hi, zp);
  loss_kernel<<<dim3(1), dim3(1024), 0, stream>>>(zp, lo, hi, out);
}